// Round 2
// baseline (2155.857 us; speedup 1.0000x reference)
//
#include <hip/hip_runtime.h>
#include <hip/hip_bf16.h>

#define L_LAYERS 16
#define H_DIM    128
#define X_IN_    47508
#define X_TOT_   47764
#define K_TOT_   47636   // X_IN + H (static part of K)
#define BS_      128
#define V_T_     3620
#define G4_      512

typedef __attribute__((ext_vector_type(8))) short bf16x8;
typedef __attribute__((ext_vector_type(4))) float f32x4;

__device__ __forceinline__ unsigned short f2bf(float f) {
    union { __hip_bfloat16 h; unsigned short u; } cv;
    cv.h = __float2bfloat16(f);
    return cv.u;
}

// ---------------------------------------------------------------------------
// Kernel 1: g_static[l][b][4H] = [input_x, prev_hidden[:,l]] @ W_gate[l][0:47636]
// grid = 64 layer-gates * NCH K-chunks; blockIdx = lg*NCH + s (chunk -> XCD).
// 128x128 output tile, K-loop in 64-steps, bf16 MFMA 16x16x32, fp32 accum.
// A staged in LDS (bf16, XOR swizzle); B direct global->frag (k-strided).
// NCH=16 -> 1024 blocks = 4 blocks/CU (occupancy fix vs round 1's 2/CU).
// ---------------------------------------------------------------------------
template<int NCH>
__global__ __launch_bounds__(256, 4)
void gemm_static_kernel(const float* __restrict__ input_x,
                        const float* __restrict__ prev_hidden,
                        const float* __restrict__ Wi,
                        const float* __restrict__ Wf,
                        const float* __restrict__ Ws,
                        const float* __restrict__ Wo,
                        float* __restrict__ partials)
{
    constexpr int KCH = (NCH == 16) ? 2944 : 5952;  // multiple of 64
    const int bid   = blockIdx.x;
    const int s     = bid & (NCH - 1);
    const int lg    = bid / NCH;
    const int layer = lg >> 2;
    const int gate  = lg & 3;
    const float* W;
    if      (gate == 0) W = Wi;
    else if (gate == 1) W = Wf;
    else if (gate == 2) W = Ws;
    else                W = Wo;
    W += (size_t)layer * X_TOT_ * H_DIM;

    const int k_begin = s * KCH;
    const int k_end   = (s == NCH - 1) ? K_TOT_ : (k_begin + KCH);
    const int NT      = (k_end - k_begin + 63) >> 6;

    const int tid  = threadIdx.x;
    const int lane = tid & 63;
    const int wv   = tid >> 6;     // wave 0..3 -> N cols [wv*32, wv*32+32)
    const int l15  = lane & 15;
    const int lg4  = lane >> 4;
    const int ar   = tid >> 4;     // A staging base row 0..15
    const int ac4  = tid & 15;     // A staging 16B column

    __shared__ unsigned short A_lds[128 * 64];   // bf16 [row][k], 16B-chunk XOR swizzle

    f32x4 acc[8][2];
    {
        f32x4 z = {0.f, 0.f, 0.f, 0.f};
        #pragma unroll
        for (int i = 0; i < 8; ++i)
            #pragma unroll
            for (int j = 0; j < 2; ++j)
                acc[i][j] = z;
    }

    float4 aq[8];   // A staging regs (tile t fp32)
    float  bq[32];  // B staging regs (tile t fp32)

    auto loadA = [&](int t) {
        const int k0 = k_begin + (t << 6);
        const int kk = k0 + ac4 * 4;
        if (k0 + 64 <= X_IN_) {
            #pragma unroll
            for (int rep = 0; rep < 8; ++rep) {
                const int r = rep * 16 + ar;
                aq[rep] = *reinterpret_cast<const float4*>(input_x + (size_t)r * X_IN_ + kk);
            }
        } else {
            #pragma unroll
            for (int rep = 0; rep < 8; ++rep) {
                const int r = rep * 16 + ar;
                float v[4];
                #pragma unroll
                for (int j = 0; j < 4; ++j) {
                    const int k = kk + j;
                    float x = 0.f;
                    if (k < X_IN_)
                        x = input_x[(size_t)r * X_IN_ + k];
                    else if (k < K_TOT_)
                        x = prev_hidden[((size_t)r * L_LAYERS + layer) * H_DIM + (k - X_IN_)];
                    v[j] = x;
                }
                aq[rep] = make_float4(v[0], v[1], v[2], v[3]);
            }
        }
    };

    auto loadB = [&](int t) {
        const int k0 = k_begin + (t << 6);
        const bool full = (k0 + 64 <= k_end);
        #pragma unroll
        for (int ks = 0; ks < 2; ++ks)
            #pragma unroll
            for (int ni = 0; ni < 2; ++ni) {
                const int c  = wv * 32 + ni * 16 + l15;
                const int kb = k0 + ks * 32 + lg4 * 8;
                const float* p = W + (size_t)kb * H_DIM + c;
                if (full) {
                    #pragma unroll
                    for (int j = 0; j < 8; ++j)
                        bq[(ks * 2 + ni) * 8 + j] = p[(size_t)j * H_DIM];
                } else {
                    #pragma unroll
                    for (int j = 0; j < 8; ++j)
                        bq[(ks * 2 + ni) * 8 + j] = (kb + j < k_end) ? p[(size_t)j * H_DIM] : 0.f;
                }
            }
    };

    auto writeA = [&]() {
        #pragma unroll
        for (int rep = 0; rep < 8; ++rep) {
            const int r = rep * 16 + ar;
            uint2 pk;
            pk.x = (unsigned)f2bf(aq[rep].x) | ((unsigned)f2bf(aq[rep].y) << 16);
            pk.y = (unsigned)f2bf(aq[rep].z) | ((unsigned)f2bf(aq[rep].w) << 16);
            const int c8  = ac4 >> 1;
            const int off = r * 128 + ((c8 ^ (r & 7)) << 4) + ((ac4 & 1) << 3);
            *reinterpret_cast<uint2*>(reinterpret_cast<char*>(A_lds) + off) = pk;
        }
    };

    bf16x8 bfrag[2][2];
    auto cvtB = [&]() {
        #pragma unroll
        for (int f = 0; f < 4; ++f) {
            bf16x8 v;
            #pragma unroll
            for (int j = 0; j < 8; ++j)
                v[j] = (short)f2bf(bq[f * 8 + j]);
            bfrag[f >> 1][f & 1] = v;
        }
    };

    auto mma = [&]() {
        #pragma unroll
        for (int ks = 0; ks < 2; ++ks) {
            #pragma unroll
            for (int mi = 0; mi < 8; ++mi) {
                const int r   = mi * 16 + l15;
                const int off = r * 128 + (((ks * 4 + lg4) ^ (l15 & 7)) << 4);
                const bf16x8 a = *reinterpret_cast<const bf16x8*>(
                    reinterpret_cast<const char*>(A_lds) + off);
                acc[mi][0] = __builtin_amdgcn_mfma_f32_16x16x32_bf16(a, bfrag[ks][0], acc[mi][0], 0, 0, 0);
                acc[mi][1] = __builtin_amdgcn_mfma_f32_16x16x32_bf16(a, bfrag[ks][1], acc[mi][1], 0, 0, 0);
            }
        }
    };

    loadA(0);
    loadB(0);
    for (int t = 0; t < NT; ++t) {
        __syncthreads();          // previous MFMA phase done reading A_lds
        writeA();                 // waits A loads (tile t), converts, stages
        cvtB();                   // waits B loads (tile t) -> fragments
        if (t + 1 < NT) { loadA(t + 1); loadB(t + 1); }  // prefetch overlaps MFMA
        __syncthreads();          // A_lds ready
        mma();
    }

    // Store partials[((s*L + layer)*BS + r)*512 + gate*128 + c]
    float* outp = partials + (size_t)(s * L_LAYERS + layer) * BS_ * G4_;
    #pragma unroll
    for (int mi = 0; mi < 8; ++mi)
        #pragma unroll
        for (int ni = 0; ni < 2; ++ni)
            #pragma unroll
            for (int rg = 0; rg < 4; ++rg) {
                const int r = mi * 16 + lg4 * 4 + rg;
                const int c = wv * 32 + ni * 16 + l15;
                outp[(size_t)r * G4_ + gate * 128 + c] = acc[mi][ni][rg];
            }
}

// ---------------------------------------------------------------------------
// Kernel 2: sequential tail. One block per batch row.
// Wp dot restructured: batches of 16 independent loads -> 8 latency batches
// per layer instead of 32; partial sums prefetched before the dot.
// ---------------------------------------------------------------------------
template<int NCH>
__global__ __launch_bounds__(512)
void lstm_tail_kernel(const float* __restrict__ partials,
                      const float* __restrict__ Wi, const float* __restrict__ Wf,
                      const float* __restrict__ Ws, const float* __restrict__ Wo,
                      const float* __restrict__ bi, const float* __restrict__ bfv,
                      const float* __restrict__ bs, const float* __restrict__ bo,
                      const float* __restrict__ old_states,
                      float* __restrict__ flat_hidden)
{
    const int b    = blockIdx.x;
    const int n    = threadIdx.x;   // 0..511
    const int gate = n >> 7;
    const int c    = n & 127;
    __shared__ float prev[H_DIM];
    __shared__ float gbuf[G4_];
    const float* Wsel = (gate == 0) ? Wi : (gate == 1) ? Wf : (gate == 2) ? Ws : Wo;
    const float* bsel = (gate == 0) ? bi : (gate == 1) ? bfv : (gate == 2) ? bs : bo;

    for (int i = 0; i < L_LAYERS; ++i) {
        // issue all partial-sum loads up front (independent, overlap the dot)
        float pv[NCH];
        #pragma unroll
        for (int s2 = 0; s2 < NCH; ++s2)
            pv[s2] = partials[((size_t)(s2 * L_LAYERS + i) * BS_ + b) * G4_ + n];

        float acc = bsel[i * H_DIM + c];
        if (i > 0) {
            const float* Wp = Wsel + ((size_t)i * X_TOT_ + X_IN_ + H_DIM) * H_DIM + c;
            #pragma unroll
            for (int h0 = 0; h0 < H_DIM; h0 += 16) {
                float w[16];
                #pragma unroll
                for (int j = 0; j < 16; ++j)
                    w[j] = Wp[(size_t)(h0 + j) * H_DIM];   // 16 independent loads
                #pragma unroll
                for (int j = 0; j < 16; ++j)
                    acc += prev[h0 + j] * w[j];            // prev[] broadcast from LDS
            }
        }
        #pragma unroll
        for (int s2 = 0; s2 < NCH; ++s2)
            acc += pv[s2];

        gbuf[n] = acc;
        __syncthreads();
        if (n < H_DIM) {
            const float ig = 1.f / (1.f + expf(-gbuf[n]));
            const float fg = 1.f / (1.f + expf(-gbuf[128 + n]));
            const float sg = tanhf(gbuf[256 + n]);
            const float og = 1.f / (1.f + expf(-gbuf[384 + n]));
            const float st = fg * old_states[((size_t)i * BS_ + b) * H_DIM + n] + ig * sg;
            const float nh = og * tanhf(st);
            flat_hidden[(size_t)b * (L_LAYERS * H_DIM) + i * H_DIM + n] = nh;
            prev[n] = nh;
        }
        __syncthreads();
    }
}

// ---------------------------------------------------------------------------
// Kernel 3: out[128][3620] = flat_hidden[128][2048] @ Wy[2048][3620].
// K split across blockIdx.y (TPS kt-tiles each) -> 456 blocks; partial
// slices summed by reduce_out_kernel. (Round 1: 114 blocks, latency-bound.)
// ---------------------------------------------------------------------------
__global__ __launch_bounds__(256, 4)
void gemm_out_kernel(const float* __restrict__ flat_hidden,
                     const float* __restrict__ Wy,
                     float* __restrict__ outbuf,   // [KS][128][3620]
                     int tps)
{
    const int tid  = threadIdx.x;
    const int lane = tid & 63;
    const int wv   = tid >> 6;
    const int l15  = lane & 15;
    const int lg4  = lane >> 4;
    const int n0   = blockIdx.x * 32;
    const int m0   = wv * 32;
    const int kt0  = blockIdx.y * tps;

    f32x4 acc[2][2];
    {
        f32x4 z = {0.f, 0.f, 0.f, 0.f};
        #pragma unroll
        for (int i = 0; i < 2; ++i)
            #pragma unroll
            for (int j = 0; j < 2; ++j)
                acc[i][j] = z;
    }

    for (int kt = kt0; kt < kt0 + tps; ++kt) {
        const int k0 = kt * 32 + lg4 * 8;
        bf16x8 afr[2], bfr[2];
        #pragma unroll
        for (int mi = 0; mi < 2; ++mi) {
            const float* ap = flat_hidden + (size_t)(m0 + mi * 16 + l15) * (L_LAYERS * H_DIM) + k0;
            const float4 a0 = *reinterpret_cast<const float4*>(ap);
            const float4 a1 = *reinterpret_cast<const float4*>(ap + 4);
            bf16x8 v;
            v[0] = (short)f2bf(a0.x); v[1] = (short)f2bf(a0.y);
            v[2] = (short)f2bf(a0.z); v[3] = (short)f2bf(a0.w);
            v[4] = (short)f2bf(a1.x); v[5] = (short)f2bf(a1.y);
            v[6] = (short)f2bf(a1.z); v[7] = (short)f2bf(a1.w);
            afr[mi] = v;
        }
        #pragma unroll
        for (int ni = 0; ni < 2; ++ni) {
            const int c = n0 + ni * 16 + l15;
            bf16x8 v;
            if (c < V_T_) {
                const float* bp = Wy + (size_t)k0 * V_T_ + c;
                #pragma unroll
                for (int j = 0; j < 8; ++j)
                    v[j] = (short)f2bf(bp[(size_t)j * V_T_]);
            } else {
                #pragma unroll
                for (int j = 0; j < 8; ++j) v[j] = 0;
            }
            bfr[ni] = v;
        }
        #pragma unroll
        for (int mi = 0; mi < 2; ++mi)
            #pragma unroll
            for (int ni = 0; ni < 2; ++ni)
                acc[mi][ni] = __builtin_amdgcn_mfma_f32_16x16x32_bf16(afr[mi], bfr[ni], acc[mi][ni], 0, 0, 0);
    }

    float* dst = outbuf + (size_t)blockIdx.y * BS_ * V_T_;
    #pragma unroll
    for (int mi = 0; mi < 2; ++mi)
        #pragma unroll
        for (int ni = 0; ni < 2; ++ni) {
            const int c = n0 + ni * 16 + l15;
            if (c < V_T_) {
                #pragma unroll
                for (int rg = 0; rg < 4; ++rg) {
                    const int r = m0 + mi * 16 + lg4 * 4 + rg;
                    dst[(size_t)r * V_T_ + c] = acc[mi][ni][rg];
                }
            }
        }
}

__global__ __launch_bounds__(256)
void reduce_out_kernel(const float* __restrict__ p, float* __restrict__ out, int ks)
{
    const int N4  = (BS_ * V_T_) / 4;   // 115840
    const int idx = blockIdx.x * 256 + threadIdx.x;
    if (idx >= N4) return;
    float4 a = reinterpret_cast<const float4*>(p)[idx];
    for (int s2 = 1; s2 < ks; ++s2) {
        const float4 b2 = reinterpret_cast<const float4*>(p + (size_t)s2 * BS_ * V_T_)[idx];
        a.x += b2.x; a.y += b2.y; a.z += b2.z; a.w += b2.w;
    }
    reinterpret_cast<float4*>(out)[idx] = a;
}

// ---------------------------------------------------------------------------
extern "C" void kernel_launch(void* const* d_in, const int* in_sizes, int n_in,
                              void* d_out, int out_size, void* d_ws, size_t ws_size,
                              hipStream_t stream)
{
    (void)in_sizes; (void)n_in; (void)out_size;
    const float* input_x     = (const float*)d_in[0];
    const float* prev_hidden = (const float*)d_in[1];
    const float* old_states  = (const float*)d_in[2];
    const float* Wi = (const float*)d_in[3];
    const float* bi = (const float*)d_in[4];
    const float* Wf = (const float*)d_in[5];
    const float* bfv = (const float*)d_in[6];
    const float* Wo = (const float*)d_in[7];
    const float* bo = (const float*)d_in[8];
    const float* Ws = (const float*)d_in[9];
    const float* bs = (const float*)d_in[10];
    const float* Wy = (const float*)d_in[11];
    float* out = (float*)d_out;

    const size_t flat_bytes = (size_t)BS_ * L_LAYERS * H_DIM * sizeof(float); // 1 MiB
    const size_t k3p_bytes  = (size_t)4 * BS_ * V_T_ * sizeof(float);         // ~7.1 MiB
    const size_t p16_bytes  = (size_t)16 * L_LAYERS * BS_ * G4_ * sizeof(float); // 64 MiB
    const size_t p8_bytes   = (size_t)8  * L_LAYERS * BS_ * G4_ * sizeof(float); // 32 MiB

    int nch = 8, ks = 1;
    if (ws_size >= p16_bytes + flat_bytes + k3p_bytes)      { nch = 16; ks = 4; }
    else if (ws_size >= p8_bytes + flat_bytes + k3p_bytes)  { nch = 8;  ks = 4; }

    float* partials    = (float*)d_ws;
    const size_t pbytes = (nch == 16) ? p16_bytes : p8_bytes;
    float* flat_hidden = (float*)((char*)d_ws + pbytes);
    float* k3p         = (float*)((char*)d_ws + pbytes + flat_bytes);

    if (nch == 16)
        gemm_static_kernel<16><<<dim3(64 * 16), dim3(256), 0, stream>>>(
            input_x, prev_hidden, Wi, Wf, Ws, Wo, partials);
    else
        gemm_static_kernel<8><<<dim3(64 * 8), dim3(256), 0, stream>>>(
            input_x, prev_hidden, Wi, Wf, Ws, Wo, partials);

    if (nch == 16)
        lstm_tail_kernel<16><<<dim3(BS_), dim3(512), 0, stream>>>(
            partials, Wi, Wf, Ws, Wo, bi, bfv, bs, bo, old_states, flat_hidden);
    else
        lstm_tail_kernel<8><<<dim3(BS_), dim3(512), 0, stream>>>(
            partials, Wi, Wf, Ws, Wo, bi, bfv, bs, bo, old_states, flat_hidden);

    if (ks == 4) {
        gemm_out_kernel<<<dim3((V_T_ + 31) / 32, 4), dim3(256), 0, stream>>>(
            flat_hidden, Wy, k3p, 16);
        reduce_out_kernel<<<dim3((BS_ * V_T_ / 4 + 255) / 256), dim3(256), 0, stream>>>(
            k3p, out, 4);
    } else {
        gemm_out_kernel<<<dim3((V_T_ + 31) / 32, 1), dim3(256), 0, stream>>>(
            flat_hidden, Wy, out, 64);
    }
}

// Round 3
// 710.143 us; speedup vs baseline: 3.0358x; 3.0358x over previous
//
#include <hip/hip_runtime.h>
#include <hip/hip_bf16.h>

#define L_LAYERS 16
#define H_DIM    128
#define X_IN_    47508
#define X_TOT_   47764
#define K_TOT_   47636   // X_IN + H (static part of K)
#define BS_      128
#define V_T_     3620
#define G4_      512
#define NCH_     8
#define KCH_     5952    // 93*64; last chunk = 47636-7*5952 = 5972 (94 tiles, guarded)

typedef __attribute__((ext_vector_type(8))) short bf16x8;
typedef __attribute__((ext_vector_type(4))) float f32x4;

__device__ __forceinline__ unsigned short f2bf(float f) {
    union { __hip_bfloat16 h; unsigned short u; } cv;
    cv.h = __float2bfloat16(f);
    return cv.u;
}

// ---------------------------------------------------------------------------
// Kernel 1: g_static[l][b][4H] = [input_x, prev_hidden[:,l]] @ W_gate[l][0:47636]
// 512 threads / 8 waves per block (R2 lesson: unified VGPR+AGPR cap is 128 at
// 16 waves/CU — acc must be split across waves, not packed per thread).
// Wave w: rows [(w>>2)*64,+64) x cols [(w&3)*32,+32). Per-thread regs ~115.
// grid = 64 layer-gates * 8 K-chunks = 512 blocks = 2 blocks/CU = 16 waves/CU.
// ---------------------------------------------------------------------------
__global__ __launch_bounds__(512, 4)
void gemm_static_kernel(const float* __restrict__ input_x,
                        const float* __restrict__ prev_hidden,
                        const float* __restrict__ Wi,
                        const float* __restrict__ Wf,
                        const float* __restrict__ Ws,
                        const float* __restrict__ Wo,
                        float* __restrict__ partials)
{
    const int bid   = blockIdx.x;
    const int s     = bid & (NCH_ - 1);
    const int lg    = bid / NCH_;
    const int layer = lg >> 2;
    const int gate  = lg & 3;
    const float* W;
    if      (gate == 0) W = Wi;
    else if (gate == 1) W = Wf;
    else if (gate == 2) W = Ws;
    else                W = Wo;
    W += (size_t)layer * X_TOT_ * H_DIM;

    const int k_begin = s * KCH_;
    const int k_end   = (s == NCH_ - 1) ? K_TOT_ : (k_begin + KCH_);
    const int NT      = (k_end - k_begin + 63) >> 6;

    const int tid  = threadIdx.x;
    const int lane = tid & 63;
    const int wv   = tid >> 6;     // 0..7
    const int mh   = wv >> 2;      // M half: rows [mh*64, +64)
    const int nw   = wv & 3;       // N quarter: cols [nw*32, +32)
    const int l15  = lane & 15;
    const int lg4  = lane >> 4;
    const int ar   = tid >> 4;     // A staging base row 0..31
    const int ac4  = tid & 15;     // A staging 16B column

    __shared__ unsigned short A_lds[128 * 64];   // bf16 [row][k], 16B-chunk XOR swizzle

    f32x4 acc[4][2];
    {
        f32x4 z = {0.f, 0.f, 0.f, 0.f};
        #pragma unroll
        for (int i = 0; i < 4; ++i)
            #pragma unroll
            for (int j = 0; j < 2; ++j)
                acc[i][j] = z;
    }

    float4 aq[4];   // A staging regs (tile t fp32): rows rep*32+ar
    float  bq[32];  // B staging regs (tile t fp32): this wave's 32 cols x 64 k

    auto loadA = [&](int t) {
        const int k0 = k_begin + (t << 6);
        const int kk = k0 + ac4 * 4;
        if (k0 + 64 <= X_IN_) {
            #pragma unroll
            for (int rep = 0; rep < 4; ++rep) {
                const int r = rep * 32 + ar;
                aq[rep] = *reinterpret_cast<const float4*>(input_x + (size_t)r * X_IN_ + kk);
            }
        } else {
            #pragma unroll
            for (int rep = 0; rep < 4; ++rep) {
                const int r = rep * 32 + ar;
                float v[4];
                #pragma unroll
                for (int j = 0; j < 4; ++j) {
                    const int k = kk + j;
                    float x = 0.f;
                    if (k < X_IN_)
                        x = input_x[(size_t)r * X_IN_ + k];
                    else if (k < K_TOT_)
                        x = prev_hidden[((size_t)r * L_LAYERS + layer) * H_DIM + (k - X_IN_)];
                    v[j] = x;
                }
                aq[rep] = make_float4(v[0], v[1], v[2], v[3]);
            }
        }
    };

    auto loadB = [&](int t) {
        const int k0 = k_begin + (t << 6);
        const bool full = (k0 + 64 <= k_end);
        #pragma unroll
        for (int ks = 0; ks < 2; ++ks)
            #pragma unroll
            for (int ni = 0; ni < 2; ++ni) {
                const int c  = nw * 32 + ni * 16 + l15;
                const int kb = k0 + ks * 32 + lg4 * 8;
                const float* p = W + (size_t)kb * H_DIM + c;
                if (full) {
                    #pragma unroll
                    for (int j = 0; j < 8; ++j)
                        bq[(ks * 2 + ni) * 8 + j] = p[(size_t)j * H_DIM];
                } else {
                    #pragma unroll
                    for (int j = 0; j < 8; ++j)
                        bq[(ks * 2 + ni) * 8 + j] = (kb + j < k_end) ? p[(size_t)j * H_DIM] : 0.f;
                }
            }
    };

    auto writeA = [&]() {
        #pragma unroll
        for (int rep = 0; rep < 4; ++rep) {
            const int r = rep * 32 + ar;
            uint2 pk;
            pk.x = (unsigned)f2bf(aq[rep].x) | ((unsigned)f2bf(aq[rep].y) << 16);
            pk.y = (unsigned)f2bf(aq[rep].z) | ((unsigned)f2bf(aq[rep].w) << 16);
            const int c8  = ac4 >> 1;
            const int off = r * 128 + ((c8 ^ (r & 7)) << 4) + ((ac4 & 1) << 3);
            *reinterpret_cast<uint2*>(reinterpret_cast<char*>(A_lds) + off) = pk;
        }
    };

    bf16x8 bfrag[2][2];
    auto cvtB = [&]() {
        #pragma unroll
        for (int f = 0; f < 4; ++f) {
            bf16x8 v;
            #pragma unroll
            for (int j = 0; j < 8; ++j)
                v[j] = (short)f2bf(bq[f * 8 + j]);
            bfrag[f >> 1][f & 1] = v;
        }
    };

    auto mma = [&]() {
        #pragma unroll
        for (int ks = 0; ks < 2; ++ks) {
            #pragma unroll
            for (int mi = 0; mi < 4; ++mi) {
                const int r   = mh * 64 + mi * 16 + l15;
                const int off = r * 128 + (((ks * 4 + lg4) ^ (l15 & 7)) << 4);
                const bf16x8 a = *reinterpret_cast<const bf16x8*>(
                    reinterpret_cast<const char*>(A_lds) + off);
                acc[mi][0] = __builtin_amdgcn_mfma_f32_16x16x32_bf16(a, bfrag[ks][0], acc[mi][0], 0, 0, 0);
                acc[mi][1] = __builtin_amdgcn_mfma_f32_16x16x32_bf16(a, bfrag[ks][1], acc[mi][1], 0, 0, 0);
            }
        }
    };

    loadA(0);
    loadB(0);
    for (int t = 0; t < NT; ++t) {
        __syncthreads();          // previous MFMA phase done reading A_lds
        writeA();                 // waits A loads (tile t), converts, stages
        cvtB();                   // waits B loads (tile t) -> fragments
        if (t + 1 < NT) { loadA(t + 1); loadB(t + 1); }  // prefetch overlaps MFMA
        __syncthreads();          // A_lds ready
        mma();
    }

    // Store partials[((s*L + layer)*BS + r)*512 + gate*128 + c]
    float* outp = partials + (size_t)(s * L_LAYERS + layer) * BS_ * G4_;
    #pragma unroll
    for (int mi = 0; mi < 4; ++mi)
        #pragma unroll
        for (int ni = 0; ni < 2; ++ni)
            #pragma unroll
            for (int rg = 0; rg < 4; ++rg) {
                const int r = mh * 64 + mi * 16 + lg4 * 4 + rg;
                const int c = nw * 32 + ni * 16 + l15;
                outp[(size_t)r * G4_ + gate * 128 + c] = acc[mi][ni][rg];
            }
}

// ---------------------------------------------------------------------------
// Kernel 2: sequential tail. One block per batch row. (R2 version: batched
// independent loads; measured ~fast — total non-GEMM remainder was ~60us.)
// ---------------------------------------------------------------------------
__global__ __launch_bounds__(512)
void lstm_tail_kernel(const float* __restrict__ partials,
                      const float* __restrict__ Wi, const float* __restrict__ Wf,
                      const float* __restrict__ Ws, const float* __restrict__ Wo,
                      const float* __restrict__ bi, const float* __restrict__ bfv,
                      const float* __restrict__ bs, const float* __restrict__ bo,
                      const float* __restrict__ old_states,
                      float* __restrict__ flat_hidden)
{
    const int b    = blockIdx.x;
    const int n    = threadIdx.x;   // 0..511
    const int gate = n >> 7;
    const int c    = n & 127;
    __shared__ float prev[H_DIM];
    __shared__ float gbuf[G4_];
    const float* Wsel = (gate == 0) ? Wi : (gate == 1) ? Wf : (gate == 2) ? Ws : Wo;
    const float* bsel = (gate == 0) ? bi : (gate == 1) ? bfv : (gate == 2) ? bs : bo;

    for (int i = 0; i < L_LAYERS; ++i) {
        float pv[NCH_];
        #pragma unroll
        for (int s2 = 0; s2 < NCH_; ++s2)
            pv[s2] = partials[((size_t)(s2 * L_LAYERS + i) * BS_ + b) * G4_ + n];

        float acc = bsel[i * H_DIM + c];
        if (i > 0) {
            const float* Wp = Wsel + ((size_t)i * X_TOT_ + X_IN_ + H_DIM) * H_DIM + c;
            #pragma unroll
            for (int h0 = 0; h0 < H_DIM; h0 += 16) {
                float w[16];
                #pragma unroll
                for (int j = 0; j < 16; ++j)
                    w[j] = Wp[(size_t)(h0 + j) * H_DIM];   // 16 independent loads
                #pragma unroll
                for (int j = 0; j < 16; ++j)
                    acc += prev[h0 + j] * w[j];
            }
        }
        #pragma unroll
        for (int s2 = 0; s2 < NCH_; ++s2)
            acc += pv[s2];

        gbuf[n] = acc;
        __syncthreads();
        if (n < H_DIM) {
            const float ig = 1.f / (1.f + expf(-gbuf[n]));
            const float fg = 1.f / (1.f + expf(-gbuf[128 + n]));
            const float sg = tanhf(gbuf[256 + n]);
            const float og = 1.f / (1.f + expf(-gbuf[384 + n]));
            const float st = fg * old_states[((size_t)i * BS_ + b) * H_DIM + n] + ig * sg;
            const float nh = og * tanhf(st);
            flat_hidden[(size_t)b * (L_LAYERS * H_DIM) + i * H_DIM + n] = nh;
            prev[n] = nh;
        }
        __syncthreads();
    }
}

// ---------------------------------------------------------------------------
// Kernel 3: out[128][3620] = flat_hidden[128][2048] @ Wy[2048][3620].
// K split 4 ways across blockIdx.y -> 456 blocks; reduce kernel sums.
// ---------------------------------------------------------------------------
__global__ __launch_bounds__(256, 4)
void gemm_out_kernel(const float* __restrict__ flat_hidden,
                     const float* __restrict__ Wy,
                     float* __restrict__ outbuf,   // [4][128][3620]
                     int tps)
{
    const int tid  = threadIdx.x;
    const int lane = tid & 63;
    const int wv   = tid >> 6;
    const int l15  = lane & 15;
    const int lg4  = lane >> 4;
    const int n0   = blockIdx.x * 32;
    const int m0   = wv * 32;
    const int kt0  = blockIdx.y * tps;

    f32x4 acc[2][2];
    {
        f32x4 z = {0.f, 0.f, 0.f, 0.f};
        #pragma unroll
        for (int i = 0; i < 2; ++i)
            #pragma unroll
            for (int j = 0; j < 2; ++j)
                acc[i][j] = z;
    }

    for (int kt = kt0; kt < kt0 + tps; ++kt) {
        const int k0 = kt * 32 + lg4 * 8;
        bf16x8 afr[2], bfr[2];
        #pragma unroll
        for (int mi = 0; mi < 2; ++mi) {
            const float* ap = flat_hidden + (size_t)(m0 + mi * 16 + l15) * (L_LAYERS * H_DIM) + k0;
            const float4 a0 = *reinterpret_cast<const float4*>(ap);
            const float4 a1 = *reinterpret_cast<const float4*>(ap + 4);
            bf16x8 v;
            v[0] = (short)f2bf(a0.x); v[1] = (short)f2bf(a0.y);
            v[2] = (short)f2bf(a0.z); v[3] = (short)f2bf(a0.w);
            v[4] = (short)f2bf(a1.x); v[5] = (short)f2bf(a1.y);
            v[6] = (short)f2bf(a1.z); v[7] = (short)f2bf(a1.w);
            afr[mi] = v;
        }
        #pragma unroll
        for (int ni = 0; ni < 2; ++ni) {
            const int c = n0 + ni * 16 + l15;
            bf16x8 v;
            if (c < V_T_) {
                const float* bp = Wy + (size_t)k0 * V_T_ + c;
                #pragma unroll
                for (int j = 0; j < 8; ++j)
                    v[j] = (short)f2bf(bp[(size_t)j * V_T_]);
            } else {
                #pragma unroll
                for (int j = 0; j < 8; ++j) v[j] = 0;
            }
            bfr[ni] = v;
        }
        #pragma unroll
        for (int mi = 0; mi < 2; ++mi)
            #pragma unroll
            for (int ni = 0; ni < 2; ++ni)
                acc[mi][ni] = __builtin_amdgcn_mfma_f32_16x16x32_bf16(afr[mi], bfr[ni], acc[mi][ni], 0, 0, 0);
    }

    float* dst = outbuf + (size_t)blockIdx.y * BS_ * V_T_;
    #pragma unroll
    for (int mi = 0; mi < 2; ++mi)
        #pragma unroll
        for (int ni = 0; ni < 2; ++ni) {
            const int c = n0 + ni * 16 + l15;
            if (c < V_T_) {
                #pragma unroll
                for (int rg = 0; rg < 4; ++rg) {
                    const int r = m0 + mi * 16 + lg4 * 4 + rg;
                    dst[(size_t)r * V_T_ + c] = acc[mi][ni][rg];
                }
            }
        }
}

__global__ __launch_bounds__(256)
void reduce_out_kernel(const float* __restrict__ p, float* __restrict__ out, int ks)
{
    const int N4  = (BS_ * V_T_) / 4;   // 115840
    const int idx = blockIdx.x * 256 + threadIdx.x;
    if (idx >= N4) return;
    float4 a = reinterpret_cast<const float4*>(p)[idx];
    for (int s2 = 1; s2 < ks; ++s2) {
        const float4 b2 = reinterpret_cast<const float4*>(p + (size_t)s2 * BS_ * V_T_)[idx];
        a.x += b2.x; a.y += b2.y; a.z += b2.z; a.w += b2.w;
    }
    reinterpret_cast<float4*>(out)[idx] = a;
}

// ---------------------------------------------------------------------------
extern "C" void kernel_launch(void* const* d_in, const int* in_sizes, int n_in,
                              void* d_out, int out_size, void* d_ws, size_t ws_size,
                              hipStream_t stream)
{
    (void)in_sizes; (void)n_in; (void)out_size;
    const float* input_x     = (const float*)d_in[0];
    const float* prev_hidden = (const float*)d_in[1];
    const float* old_states  = (const float*)d_in[2];
    const float* Wi = (const float*)d_in[3];
    const float* bi = (const float*)d_in[4];
    const float* Wf = (const float*)d_in[5];
    const float* bfv = (const float*)d_in[6];
    const float* Wo = (const float*)d_in[7];
    const float* bo = (const float*)d_in[8];
    const float* Ws = (const float*)d_in[9];
    const float* bs = (const float*)d_in[10];
    const float* Wy = (const float*)d_in[11];
    float* out = (float*)d_out;

    const size_t pbytes     = (size_t)NCH_ * L_LAYERS * BS_ * G4_ * sizeof(float); // 32 MiB
    const size_t flat_bytes = (size_t)BS_ * L_LAYERS * H_DIM * sizeof(float);      // 1 MiB
    const size_t k3p_bytes  = (size_t)4 * BS_ * V_T_ * sizeof(float);              // ~7.1 MiB

    float* partials    = (float*)d_ws;
    float* flat_hidden = (float*)((char*)d_ws + pbytes);
    float* k3p         = (float*)((char*)d_ws + pbytes + flat_bytes);
    const bool split_k3 = (ws_size >= pbytes + flat_bytes + k3p_bytes);

    gemm_static_kernel<<<dim3(64 * NCH_), dim3(512), 0, stream>>>(
        input_x, prev_hidden, Wi, Wf, Ws, Wo, partials);

    lstm_tail_kernel<<<dim3(BS_), dim3(512), 0, stream>>>(
        partials, Wi, Wf, Ws, Wo, bi, bfv, bs, bo, old_states, flat_hidden);

    if (split_k3) {
        gemm_out_kernel<<<dim3((V_T_ + 31) / 32, 4), dim3(256), 0, stream>>>(
            flat_hidden, Wy, k3p, 16);
        reduce_out_kernel<<<dim3((BS_ * V_T_ / 4 + 255) / 256), dim3(256), 0, stream>>>(
            k3p, out, 4);
    } else {
        gemm_out_kernel<<<dim3((V_T_ + 31) / 32, 1), dim3(256), 0, stream>>>(
            flat_hidden, Wy, out, 64);
    }
}

// Round 4
// 484.442 us; speedup vs baseline: 4.4502x; 1.4659x over previous
//
#include <hip/hip_runtime.h>
#include <hip/hip_bf16.h>

#define L_LAYERS 16
#define H_DIM    128
#define X_IN_    47508
#define X_TOT_   47764
#define K_TOT_   47636   // X_IN + H (static part of K)
#define BS_      128
#define V_T_     3620
#define G4_      512

typedef __attribute__((ext_vector_type(8))) short bf16x8;
typedef __attribute__((ext_vector_type(4))) float f32x4;

__device__ __forceinline__ unsigned short f2bf(float f) {
    union { __hip_bfloat16 h; unsigned short u; } cv;
    cv.h = __float2bfloat16(f);
    return cv.u;
}

// ---------------------------------------------------------------------------
// Kernel 1: g_static[l][b][4H] = [input_x, prev_hidden[:,l]] @ W_gate[l][0:47636]
// R1 structure EXACTLY (256 thr / 4 waves, VGPR 112, no spill — R2/R3 lesson:
// never force occupancy via launch_bounds reg-cap; it spills and scratch
// traffic dominates). Occupancy comes from the grid: NCH=16 balanced K-chunks
// -> 1024 blocks = 4 blocks/CU = 16 waves/CU (R1 was grid-limited at 2/CU).
// Total K tiles = ceil(47636/64) = 745 = EXTRA*(BT+1) + (NCH-EXTRA)*BT.
// bid%8 == s%8 -> all blocks of chunk s share an XCD -> input_x slice is
// L2-resident per XCD.
// ---------------------------------------------------------------------------
template<int NCH, int BT, int EXTRA>
__global__ __launch_bounds__(256, 2)
void gemm_static_kernel(const float* __restrict__ input_x,
                        const float* __restrict__ prev_hidden,
                        const float* __restrict__ Wi,
                        const float* __restrict__ Wf,
                        const float* __restrict__ Ws,
                        const float* __restrict__ Wo,
                        float* __restrict__ partials)
{
    const int bid   = blockIdx.x;
    const int s     = bid & (NCH - 1);
    const int lg    = bid / NCH;
    const int layer = lg >> 2;
    const int gate  = lg & 3;
    const float* W;
    if      (gate == 0) W = Wi;
    else if (gate == 1) W = Wf;
    else if (gate == 2) W = Ws;
    else                W = Wo;
    W += (size_t)layer * X_TOT_ * H_DIM;

    const int k_begin = (s * BT + (s < EXTRA ? s : EXTRA)) * 64;
    const int NT      = BT + (s < EXTRA ? 1 : 0);
    const int k_end   = (k_begin + NT * 64 < K_TOT_) ? (k_begin + NT * 64) : K_TOT_;

    const int tid  = threadIdx.x;
    const int lane = tid & 63;
    const int wv   = tid >> 6;     // wave 0..3 -> N cols [wv*32, wv*32+32)
    const int l15  = lane & 15;
    const int lg4  = lane >> 4;
    const int ar   = tid >> 4;     // A staging base row 0..15
    const int ac4  = tid & 15;     // A staging 16B column

    __shared__ unsigned short A_lds[128 * 64];   // bf16 [row][k], 16B-chunk XOR swizzle

    f32x4 acc[8][2];
    {
        f32x4 z = {0.f, 0.f, 0.f, 0.f};
        #pragma unroll
        for (int i = 0; i < 8; ++i)
            #pragma unroll
            for (int j = 0; j < 2; ++j)
                acc[i][j] = z;
    }

    float4 aq[8];   // A staging regs (tile t fp32)
    float  bq[32];  // B staging regs (tile t fp32)

    auto loadA = [&](int t) {
        const int k0 = k_begin + (t << 6);
        const int kk = k0 + ac4 * 4;
        if (k0 + 64 <= X_IN_) {
            #pragma unroll
            for (int rep = 0; rep < 8; ++rep) {
                const int r = rep * 16 + ar;
                aq[rep] = *reinterpret_cast<const float4*>(input_x + (size_t)r * X_IN_ + kk);
            }
        } else {
            #pragma unroll
            for (int rep = 0; rep < 8; ++rep) {
                const int r = rep * 16 + ar;
                float v[4];
                #pragma unroll
                for (int j = 0; j < 4; ++j) {
                    const int k = kk + j;
                    float x = 0.f;
                    if (k < X_IN_)
                        x = input_x[(size_t)r * X_IN_ + k];
                    else if (k < K_TOT_)
                        x = prev_hidden[((size_t)r * L_LAYERS + layer) * H_DIM + (k - X_IN_)];
                    v[j] = x;
                }
                aq[rep] = make_float4(v[0], v[1], v[2], v[3]);
            }
        }
    };

    auto loadB = [&](int t) {
        const int k0 = k_begin + (t << 6);
        const bool full = (k0 + 64 <= k_end);
        #pragma unroll
        for (int ks = 0; ks < 2; ++ks)
            #pragma unroll
            for (int ni = 0; ni < 2; ++ni) {
                const int c  = wv * 32 + ni * 16 + l15;
                const int kb = k0 + ks * 32 + lg4 * 8;
                const float* p = W + (size_t)kb * H_DIM + c;
                if (full) {
                    #pragma unroll
                    for (int j = 0; j < 8; ++j)
                        bq[(ks * 2 + ni) * 8 + j] = p[(size_t)j * H_DIM];
                } else {
                    #pragma unroll
                    for (int j = 0; j < 8; ++j)
                        bq[(ks * 2 + ni) * 8 + j] = (kb + j < k_end) ? p[(size_t)j * H_DIM] : 0.f;
                }
            }
    };

    auto writeA = [&]() {
        #pragma unroll
        for (int rep = 0; rep < 8; ++rep) {
            const int r = rep * 16 + ar;
            uint2 pk;
            pk.x = (unsigned)f2bf(aq[rep].x) | ((unsigned)f2bf(aq[rep].y) << 16);
            pk.y = (unsigned)f2bf(aq[rep].z) | ((unsigned)f2bf(aq[rep].w) << 16);
            const int c8  = ac4 >> 1;
            const int off = r * 128 + ((c8 ^ (r & 7)) << 4) + ((ac4 & 1) << 3);
            *reinterpret_cast<uint2*>(reinterpret_cast<char*>(A_lds) + off) = pk;
        }
    };

    bf16x8 bfrag[2][2];
    auto cvtB = [&]() {
        #pragma unroll
        for (int f = 0; f < 4; ++f) {
            bf16x8 v;
            #pragma unroll
            for (int j = 0; j < 8; ++j)
                v[j] = (short)f2bf(bq[f * 8 + j]);
            bfrag[f >> 1][f & 1] = v;
        }
    };

    auto mma = [&]() {
        #pragma unroll
        for (int ks = 0; ks < 2; ++ks) {
            #pragma unroll
            for (int mi = 0; mi < 8; ++mi) {
                const int r   = mi * 16 + l15;
                const int off = r * 128 + (((ks * 4 + lg4) ^ (l15 & 7)) << 4);
                const bf16x8 a = *reinterpret_cast<const bf16x8*>(
                    reinterpret_cast<const char*>(A_lds) + off);
                acc[mi][0] = __builtin_amdgcn_mfma_f32_16x16x32_bf16(a, bfrag[ks][0], acc[mi][0], 0, 0, 0);
                acc[mi][1] = __builtin_amdgcn_mfma_f32_16x16x32_bf16(a, bfrag[ks][1], acc[mi][1], 0, 0, 0);
            }
        }
    };

    loadA(0);
    loadB(0);
    for (int t = 0; t < NT; ++t) {
        __syncthreads();          // previous MFMA phase done reading A_lds
        writeA();                 // waits A loads (tile t), converts, stages
        cvtB();                   // waits B loads (tile t) -> fragments
        if (t + 1 < NT) { loadA(t + 1); loadB(t + 1); }  // prefetch overlaps MFMA
        __syncthreads();          // A_lds ready
        mma();
    }

    // Store partials[((s*L + layer)*BS + r)*512 + gate*128 + c]
    float* outp = partials + (size_t)(s * L_LAYERS + layer) * BS_ * G4_;
    #pragma unroll
    for (int mi = 0; mi < 8; ++mi)
        #pragma unroll
        for (int ni = 0; ni < 2; ++ni)
            #pragma unroll
            for (int rg = 0; rg < 4; ++rg) {
                const int r = mi * 16 + lg4 * 4 + rg;
                const int c = wv * 32 + ni * 16 + l15;
                outp[(size_t)r * G4_ + gate * 128 + c] = acc[mi][ni][rg];
            }
}

// ---------------------------------------------------------------------------
// Kernel 2: sequential tail. One block per batch row; batched independent
// loads for the prev-layer dot (R2 version — remainder measured ~63 us total).
// ---------------------------------------------------------------------------
template<int NCH>
__global__ __launch_bounds__(512)
void lstm_tail_kernel(const float* __restrict__ partials,
                      const float* __restrict__ Wi, const float* __restrict__ Wf,
                      const float* __restrict__ Ws, const float* __restrict__ Wo,
                      const float* __restrict__ bi, const float* __restrict__ bfv,
                      const float* __restrict__ bs, const float* __restrict__ bo,
                      const float* __restrict__ old_states,
                      float* __restrict__ flat_hidden)
{
    const int b    = blockIdx.x;
    const int n    = threadIdx.x;   // 0..511
    const int gate = n >> 7;
    const int c    = n & 127;
    __shared__ float prev[H_DIM];
    __shared__ float gbuf[G4_];
    const float* Wsel = (gate == 0) ? Wi : (gate == 1) ? Wf : (gate == 2) ? Ws : Wo;
    const float* bsel = (gate == 0) ? bi : (gate == 1) ? bfv : (gate == 2) ? bs : bo;

    for (int i = 0; i < L_LAYERS; ++i) {
        float pv[NCH];
        #pragma unroll
        for (int s2 = 0; s2 < NCH; ++s2)
            pv[s2] = partials[((size_t)(s2 * L_LAYERS + i) * BS_ + b) * G4_ + n];

        float acc = bsel[i * H_DIM + c];
        if (i > 0) {
            const float* Wp = Wsel + ((size_t)i * X_TOT_ + X_IN_ + H_DIM) * H_DIM + c;
            #pragma unroll
            for (int h0 = 0; h0 < H_DIM; h0 += 16) {
                float w[16];
                #pragma unroll
                for (int j = 0; j < 16; ++j)
                    w[j] = Wp[(size_t)(h0 + j) * H_DIM];   // 16 independent loads
                #pragma unroll
                for (int j = 0; j < 16; ++j)
                    acc += prev[h0 + j] * w[j];
            }
        }
        #pragma unroll
        for (int s2 = 0; s2 < NCH; ++s2)
            acc += pv[s2];

        gbuf[n] = acc;
        __syncthreads();
        if (n < H_DIM) {
            const float ig = 1.f / (1.f + expf(-gbuf[n]));
            const float fg = 1.f / (1.f + expf(-gbuf[128 + n]));
            const float sg = tanhf(gbuf[256 + n]);
            const float og = 1.f / (1.f + expf(-gbuf[384 + n]));
            const float st = fg * old_states[((size_t)i * BS_ + b) * H_DIM + n] + ig * sg;
            const float nh = og * tanhf(st);
            flat_hidden[(size_t)b * (L_LAYERS * H_DIM) + i * H_DIM + n] = nh;
            prev[n] = nh;
        }
        __syncthreads();
    }
}

// ---------------------------------------------------------------------------
// Kernel 3: out[128][3620] = flat_hidden[128][2048] @ Wy[2048][3620].
// K split 4 ways across blockIdx.y -> 456 blocks; reduce kernel sums.
// ---------------------------------------------------------------------------
__global__ __launch_bounds__(256, 2)
void gemm_out_kernel(const float* __restrict__ flat_hidden,
                     const float* __restrict__ Wy,
                     float* __restrict__ outbuf,   // [4][128][3620]
                     int tps)
{
    const int tid  = threadIdx.x;
    const int lane = tid & 63;
    const int wv   = tid >> 6;
    const int l15  = lane & 15;
    const int lg4  = lane >> 4;
    const int n0   = blockIdx.x * 32;
    const int m0   = wv * 32;
    const int kt0  = blockIdx.y * tps;

    f32x4 acc[2][2];
    {
        f32x4 z = {0.f, 0.f, 0.f, 0.f};
        #pragma unroll
        for (int i = 0; i < 2; ++i)
            #pragma unroll
            for (int j = 0; j < 2; ++j)
                acc[i][j] = z;
    }

    for (int kt = kt0; kt < kt0 + tps; ++kt) {
        const int k0 = kt * 32 + lg4 * 8;
        bf16x8 afr[2], bfr[2];
        #pragma unroll
        for (int mi = 0; mi < 2; ++mi) {
            const float* ap = flat_hidden + (size_t)(m0 + mi * 16 + l15) * (L_LAYERS * H_DIM) + k0;
            const float4 a0 = *reinterpret_cast<const float4*>(ap);
            const float4 a1 = *reinterpret_cast<const float4*>(ap + 4);
            bf16x8 v;
            v[0] = (short)f2bf(a0.x); v[1] = (short)f2bf(a0.y);
            v[2] = (short)f2bf(a0.z); v[3] = (short)f2bf(a0.w);
            v[4] = (short)f2bf(a1.x); v[5] = (short)f2bf(a1.y);
            v[6] = (short)f2bf(a1.z); v[7] = (short)f2bf(a1.w);
            afr[mi] = v;
        }
        #pragma unroll
        for (int ni = 0; ni < 2; ++ni) {
            const int c = n0 + ni * 16 + l15;
            bf16x8 v;
            if (c < V_T_) {
                const float* bp = Wy + (size_t)k0 * V_T_ + c;
                #pragma unroll
                for (int j = 0; j < 8; ++j)
                    v[j] = (short)f2bf(bp[(size_t)j * V_T_]);
            } else {
                #pragma unroll
                for (int j = 0; j < 8; ++j) v[j] = 0;
            }
            bfr[ni] = v;
        }
        #pragma unroll
        for (int mi = 0; mi < 2; ++mi)
            #pragma unroll
            for (int ni = 0; ni < 2; ++ni)
                acc[mi][ni] = __builtin_amdgcn_mfma_f32_16x16x32_bf16(afr[mi], bfr[ni], acc[mi][ni], 0, 0, 0);
    }

    float* dst = outbuf + (size_t)blockIdx.y * BS_ * V_T_;
    #pragma unroll
    for (int mi = 0; mi < 2; ++mi)
        #pragma unroll
        for (int ni = 0; ni < 2; ++ni) {
            const int c = n0 + ni * 16 + l15;
            if (c < V_T_) {
                #pragma unroll
                for (int rg = 0; rg < 4; ++rg) {
                    const int r = m0 + mi * 16 + lg4 * 4 + rg;
                    dst[(size_t)r * V_T_ + c] = acc[mi][ni][rg];
                }
            }
        }
}

__global__ __launch_bounds__(256)
void reduce_out_kernel(const float* __restrict__ p, float* __restrict__ out, int ks)
{
    const int N4  = (BS_ * V_T_) / 4;   // 115840
    const int idx = blockIdx.x * 256 + threadIdx.x;
    if (idx >= N4) return;
    float4 a = reinterpret_cast<const float4*>(p)[idx];
    for (int s2 = 1; s2 < ks; ++s2) {
        const float4 b2 = reinterpret_cast<const float4*>(p + (size_t)s2 * BS_ * V_T_)[idx];
        a.x += b2.x; a.y += b2.y; a.z += b2.z; a.w += b2.w;
    }
    reinterpret_cast<float4*>(out)[idx] = a;
}

// ---------------------------------------------------------------------------
extern "C" void kernel_launch(void* const* d_in, const int* in_sizes, int n_in,
                              void* d_out, int out_size, void* d_ws, size_t ws_size,
                              hipStream_t stream)
{
    (void)in_sizes; (void)n_in; (void)out_size;
    const float* input_x     = (const float*)d_in[0];
    const float* prev_hidden = (const float*)d_in[1];
    const float* old_states  = (const float*)d_in[2];
    const float* Wi = (const float*)d_in[3];
    const float* bi = (const float*)d_in[4];
    const float* Wf = (const float*)d_in[5];
    const float* bfv = (const float*)d_in[6];
    const float* Wo = (const float*)d_in[7];
    const float* bo = (const float*)d_in[8];
    const float* Ws = (const float*)d_in[9];
    const float* bs = (const float*)d_in[10];
    const float* Wy = (const float*)d_in[11];
    float* out = (float*)d_out;

    const size_t flat_bytes = (size_t)BS_ * L_LAYERS * H_DIM * sizeof(float);       // 1 MiB
    const size_t k3p_bytes  = (size_t)4 * BS_ * V_T_ * sizeof(float);               // ~7.1 MiB
    const size_t p16_bytes  = (size_t)16 * L_LAYERS * BS_ * G4_ * sizeof(float);    // 64 MiB
    const size_t p8_bytes   = (size_t)8  * L_LAYERS * BS_ * G4_ * sizeof(float);    // 32 MiB

    // 745 total K-tiles: NCH=16 -> 9 chunks of 47 + 7 of 46; NCH=8 -> 1 of 94 + 7 of 93.
    const bool use16 = (ws_size >= p16_bytes + flat_bytes + k3p_bytes);
    const size_t pbytes = use16 ? p16_bytes : p8_bytes;

    float* partials    = (float*)d_ws;
    float* flat_hidden = (float*)((char*)d_ws + pbytes);
    float* k3p         = (float*)((char*)d_ws + pbytes + flat_bytes);
    const bool split_k3 = (ws_size >= pbytes + flat_bytes + k3p_bytes);

    if (use16) {
        gemm_static_kernel<16, 46, 9><<<dim3(64 * 16), dim3(256), 0, stream>>>(
            input_x, prev_hidden, Wi, Wf, Ws, Wo, partials);
        lstm_tail_kernel<16><<<dim3(BS_), dim3(512), 0, stream>>>(
            partials, Wi, Wf, Ws, Wo, bi, bfv, bs, bo, old_states, flat_hidden);
    } else {
        gemm_static_kernel<8, 93, 1><<<dim3(64 * 8), dim3(256), 0, stream>>>(
            input_x, prev_hidden, Wi, Wf, Ws, Wo, partials);
        lstm_tail_kernel<8><<<dim3(BS_), dim3(512), 0, stream>>>(
            partials, Wi, Wf, Ws, Wo, bi, bfv, bs, bo, old_states, flat_hidden);
    }

    if (split_k3) {
        gemm_out_kernel<<<dim3((V_T_ + 31) / 32, 4), dim3(256), 0, stream>>>(
            flat_hidden, Wy, k3p, 16);
        reduce_out_kernel<<<dim3((BS_ * V_T_ / 4 + 255) / 256), dim3(256), 0, stream>>>(
            k3p, out, 4);
    } else {
        gemm_out_kernel<<<dim3((V_T_ + 31) / 32, 1), dim3(256), 0, stream>>>(
            flat_hidden, Wy, out, 64);
    }
}